// Round 5
// baseline (239.020 us; speedup 1.0000x reference)
//
#include <hip/hip_runtime.h>
#include <hip/hip_bf16.h>

#define N_NODES 50000
#define N_EDGES 800000
#define N_FEAT 512
#define HIDDEN 128
#define N_CLASSES 32

typedef __attribute__((ext_vector_type(8))) short bf16x8;
typedef __attribute__((ext_vector_type(4))) float f32x4;

// round-to-nearest-even f32 -> bf16 bits
static __device__ __forceinline__ unsigned short f2bf(float f) {
    unsigned u = __float_as_uint(f);
    u += 0x7FFFu + ((u >> 16) & 1u);
    return (unsigned short)(u >> 16);
}
static __device__ __forceinline__ float bf2f(unsigned short b) {
    return __uint_as_float(((unsigned)b) << 16);
}
// unpack uint = (bf16_hi<<16)|bf16_lo
static __device__ __forceinline__ float bflo(unsigned u) { return __uint_as_float(u << 16); }
static __device__ __forceinline__ float bfhi(unsigned u) { return __uint_as_float(u & 0xFFFF0000u); }
static __device__ __forceinline__ unsigned pack2(float a, float b) {
    return (unsigned)f2bf(a) | ((unsigned)f2bf(b) << 16);
}

// ---------------- CSR build ----------------

__global__ __launch_bounds__(256) void zero_k(int* __restrict__ p) {
    int i = blockIdx.x * 256 + threadIdx.x;
    if (i < N_NODES) p[i] = 0;
}

__global__ __launch_bounds__(256) void hist_k(const int* __restrict__ src, int* __restrict__ cnt) {
    int i = blockIdx.x * 256 + threadIdx.x;
    if (i < N_EDGES) atomicAdd(&cnt[src[i]], 1);
}

__global__ __launch_bounds__(256) void scan_a(const int* __restrict__ cnt, int* __restrict__ bsum) {
    __shared__ int sd[256];
    int t = threadIdx.x;
    int i = blockIdx.x * 256 + t;
    sd[t] = (i < N_NODES) ? cnt[i] : 0;
    __syncthreads();
    for (int off = 128; off > 0; off >>= 1) {
        if (t < off) sd[t] += sd[t + off];
        __syncthreads();
    }
    if (t == 0) bsum[blockIdx.x] = sd[0];
}

__global__ __launch_bounds__(256) void scan_b(const int* __restrict__ bsum, int* __restrict__ boff) {
    __shared__ int sd[256];
    int t = threadIdx.x;
    int v = (t < 196) ? bsum[t] : 0;
    sd[t] = v;
    __syncthreads();
    for (int off = 1; off < 256; off <<= 1) {
        int xv = (t >= off) ? sd[t - off] : 0;
        __syncthreads();
        sd[t] += xv;
        __syncthreads();
    }
    if (t < 196) boff[t] = sd[t] - v;   // exclusive
}

// cnt may alias cursor — no __restrict__
__global__ __launch_bounds__(256) void scan_c(const int* cnt, const int* boff,
                                              int* row_ptr, int* cursor) {
    __shared__ int sd[256];
    int t = threadIdx.x;
    int i = blockIdx.x * 256 + t;
    int v = (i < N_NODES) ? cnt[i] : 0;
    sd[t] = v;
    __syncthreads();
    for (int off = 1; off < 256; off <<= 1) {
        int xv = (t >= off) ? sd[t - off] : 0;
        __syncthreads();
        sd[t] += xv;
        __syncthreads();
    }
    int start = boff[blockIdx.x] + (sd[t] - v);
    if (i < N_NODES) { row_ptr[i] = start; cursor[i] = start; }
    if (i == N_NODES) row_ptr[N_NODES] = N_EDGES;
}

// packed scatter: one 8B nt store per edge
__global__ __launch_bounds__(256) void scatter_k(const int* __restrict__ src, const int* __restrict__ dst,
                                                 const float* __restrict__ val, int* __restrict__ cursor,
                                                 unsigned long long* __restrict__ csr_ev) {
    int i = blockIdx.x * 256 + threadIdx.x;
    if (i >= N_EDGES) return;
    int s = src[i];
    unsigned long long packed = (unsigned long long)(unsigned)dst[i]
                              | ((unsigned long long)__float_as_uint(val[i]) << 32);
    int pos = atomicAdd(&cursor[s], 1);
    __builtin_nontemporal_store(packed, &csr_ev[pos]);
}

// ---------------- W1 transpose + bf16: W1[512][128] -> W1t[128][512] bf16 ----------------

__global__ __launch_bounds__(256) void w1conv_k(const float* __restrict__ W1,
                                                unsigned short* __restrict__ W1t) {
    int id = blockIdx.x * 256 + threadIdx.x;   // 65536
    int c = id >> 9;          // 0..127
    int k = id & 511;         // 0..511
    W1t[(size_t)c * N_FEAT + k] = f2bf(W1[(size_t)k * HIDDEN + c]);
}

// ---------------- GEMM1 via bf16 MFMA: pre1b = bf16(x @ W1) ----------------
// 64x128 tile, grid 782 (~3 blocks/CU), 4 waves: wave w -> cols w*32..w*32+31.

#define LDT 72   // shorts per LDS row (64 + 8 pad -> 144B stride, 2-way conflicts = free)

__global__ __launch_bounds__(256, 4) void gemm1_mfma(const float* __restrict__ x,
                                                     const unsigned short* __restrict__ W1t,
                                                     unsigned short* __restrict__ pre1b) {
    __shared__ short As[64 * LDT];     // 9.2 KB
    __shared__ short Bs[128 * LDT];    // 18.4 KB

    const int t = threadIdx.x;
    const int w = t >> 6;        // 0..3: col quarter
    const int l = t & 63;
    const int row0 = blockIdx.x * 64;
    const int l15 = l & 15;
    const int lhi = l >> 4;

    f32x4 acc[4][2];
#pragma unroll
    for (int m = 0; m < 4; ++m)
#pragma unroll
        for (int n = 0; n < 2; ++n) acc[m][n] = (f32x4){0.f, 0.f, 0.f, 0.f};

    for (int k0 = 0; k0 < N_FEAT; k0 += 64) {
        __syncthreads();
        // stage x tile 64x64 f32 -> bf16 (4 float4 per thread)
#pragma unroll
        for (int j = 0; j < 4; ++j) {
            int f = j * 256 + t;
            int ar = f >> 4;              // 0..63
            int ak = (f & 15) << 2;       // 0..60
            int gr = row0 + ar;
            if (gr > N_NODES - 1) gr = N_NODES - 1;
            float4 v = *(const float4*)(x + (size_t)gr * N_FEAT + k0 + ak);
            ushort4 hh;
            hh.x = f2bf(v.x); hh.y = f2bf(v.y); hh.z = f2bf(v.z); hh.w = f2bf(v.w);
            *(ushort4*)&As[ar * LDT + ak] = hh;
        }
        // stage W1t tile 128x64 bf16 (4 x 16B per thread)
#pragma unroll
        for (int j = 0; j < 4; ++j) {
            int f = j * 256 + t;
            int br = f >> 3;              // 0..127 (col index)
            int bk = (f & 7) << 3;        // 0..56 shorts
            *(bf16x8*)&Bs[br * LDT + bk] = *(const bf16x8*)(W1t + (size_t)br * N_FEAT + k0 + bk);
        }
        __syncthreads();
#pragma unroll
        for (int ks = 0; ks < 2; ++ks) {
            const int koff = ks * 32 + lhi * 8;
            bf16x8 af[4], bf[2];
#pragma unroll
            for (int m = 0; m < 4; ++m)
                af[m] = *(bf16x8*)&As[(m * 16 + l15) * LDT + koff];
#pragma unroll
            for (int n = 0; n < 2; ++n)
                bf[n] = *(bf16x8*)&Bs[(w * 32 + n * 16 + l15) * LDT + koff];
#pragma unroll
            for (int m = 0; m < 4; ++m)
#pragma unroll
                for (int n = 0; n < 2; ++n)
                    acc[m][n] = __builtin_amdgcn_mfma_f32_16x16x32_bf16(af[m], bf[n], acc[m][n], 0, 0, 0);
        }
    }
    // epilogue: C/D layout col=lane&15, row=(lane>>4)*4+reg ; write bf16
    const int c0 = w * 32;
#pragma unroll
    for (int m = 0; m < 4; ++m)
#pragma unroll
        for (int n = 0; n < 2; ++n) {
#pragma unroll
            for (int j = 0; j < 4; ++j) {
                int r = row0 + m * 16 + lhi * 4 + j;
                if (r < N_NODES) pre1b[(size_t)r * HIDDEN + c0 + n * 16 + l15] = f2bf(acc[m][n][j]);
            }
        }
}

// ---------------- SpMM1: hb = bf16(relu(A @ pre1)), one wave per node, 1 uint (2 feats)/lane ----------------

__global__ __launch_bounds__(256) void spmm1_k(const int* __restrict__ rp,
                                               const unsigned long long* __restrict__ ce,
                                               const unsigned* __restrict__ P,
                                               unsigned* __restrict__ hb) {
    const int g = threadIdx.x >> 6;
    const int lane = threadIdx.x & 63;
    const int node = blockIdx.x * 4 + g;
    if (node >= N_NODES) return;
    const int s = rp[node], e = rp[node + 1];
    float2 a0; a0.x = 0.f; a0.y = 0.f;
    float2 a1; a1.x = 0.f; a1.y = 0.f;
    int i = s;
    for (; i + 2 <= e; i += 2) {
        unsigned long long e0 = ce[i], e1 = ce[i + 1];
        int d0 = (int)(unsigned)e0, d1 = (int)(unsigned)e1;
        float v0 = __uint_as_float((unsigned)(e0 >> 32));
        float v1 = __uint_as_float((unsigned)(e1 >> 32));
        unsigned u0 = P[(size_t)d0 * 64 + lane];
        unsigned u1 = P[(size_t)d1 * 64 + lane];
        a0.x += v0 * bflo(u0); a0.y += v0 * bfhi(u0);
        a1.x += v1 * bflo(u1); a1.y += v1 * bfhi(u1);
    }
    if (i < e) {
        unsigned long long e0 = ce[i];
        int d0 = (int)(unsigned)e0;
        float v0 = __uint_as_float((unsigned)(e0 >> 32));
        unsigned u0 = P[(size_t)d0 * 64 + lane];
        a0.x += v0 * bflo(u0); a0.y += v0 * bfhi(u0);
    }
    a0.x += a1.x; a0.y += a1.y;
    a0.x = a0.x > 0.f ? a0.x : 0.f;
    a0.y = a0.y > 0.f ? a0.y : 0.f;
    hb[(size_t)node * 64 + lane] = pack2(a0.x, a0.y);
}

// ---------------- GEMM2: pre2b[50000,32] = bf16(h @ W2) ----------------

__global__ __launch_bounds__(256) void gemm2_k(const unsigned* __restrict__ hb,
                                               const float* __restrict__ W2,
                                               unsigned short* __restrict__ pre2b) {
    __shared__ float hs[32][132];
    __shared__ float w2s[HIDDEN][N_CLASSES];
    const int t = threadIdx.x;
    const int row0 = blockIdx.x * 32;
#pragma unroll
    for (int j = 0; j < 4; ++j) {        // W2: 1024 float4
        int f = j * 256 + t;
        int r = f >> 3;
        int c = (f & 7) << 2;
        *(float4*)&w2s[r][c] = *(const float4*)(W2 + (size_t)r * N_CLASSES + c);
    }
#pragma unroll
    for (int j = 0; j < 2; ++j) {        // h tile: 32 rows x 64 uints = 2048 uints
        int f = j * 256 + t;
        int r = f >> 4;                  // 0..31
        int cu = (f & 15) << 2;          // uint col 0..60 step 4
        int grr = row0 + r;
        if (grr >= N_NODES) grr = N_NODES - 1;
        uint4 u = *(const uint4*)(hb + (size_t)grr * 64 + cu);
        hs[r][2 * cu + 0] = bflo(u.x); hs[r][2 * cu + 1] = bfhi(u.x);
        hs[r][2 * cu + 2] = bflo(u.y); hs[r][2 * cu + 3] = bfhi(u.y);
        hs[r][2 * cu + 4] = bflo(u.z); hs[r][2 * cu + 5] = bfhi(u.z);
        hs[r][2 * cu + 6] = bflo(u.w); hs[r][2 * cu + 7] = bfhi(u.w);
    }
    __syncthreads();
    const int r = t >> 3;
    const int c = (t & 7) << 2;
    float4 acc; acc.x = acc.y = acc.z = acc.w = 0.f;
#pragma unroll 16
    for (int kk = 0; kk < HIDDEN; ++kk) {
        float a = hs[r][kk];
        float4 b = *(const float4*)&w2s[kk][c];
        acc.x += a * b.x; acc.y += a * b.y; acc.z += a * b.z; acc.w += a * b.w;
    }
    int grr = row0 + r;
    if (grr < N_NODES) {
        uint2 o;
        o.x = pack2(acc.x, acc.y);
        o.y = pack2(acc.z, acc.w);
        *(uint2*)&pre2b[(size_t)grr * N_CLASSES + c] = o;
    }
}

// ---------------- SpMM2: out = A @ pre2 ; 16 lanes/edge, 4 edges/iter ----------------

__global__ __launch_bounds__(256) void spmm2_k(const int* __restrict__ rp,
                                               const unsigned long long* __restrict__ ce,
                                               const unsigned* __restrict__ P2,
                                               float* __restrict__ out) {
    const int g = threadIdx.x >> 6;
    const int lane = threadIdx.x & 63;
    const int node = blockIdx.x * 4 + g;
    if (node >= N_NODES) return;
    const int s = rp[node], e = rp[node + 1];
    const int f2 = lane & 15;      // uint index: feats 2*f2, 2*f2+1
    const int par = lane >> 4;     // 0..3
    float ax = 0.f, ay = 0.f;
    for (int i = s + par; i < e; i += 4) {
        unsigned long long ed = ce[i];
        int dst = (int)(unsigned)ed;
        float v = __uint_as_float((unsigned)(ed >> 32));
        unsigned u = P2[(size_t)dst * 16 + f2];
        ax += v * bflo(u);
        ay += v * bfhi(u);
    }
    ax += __shfl_xor(ax, 16); ay += __shfl_xor(ay, 16);
    ax += __shfl_xor(ax, 32); ay += __shfl_xor(ay, 32);
    if (lane < 16) {
        float2 o; o.x = ax; o.y = ay;
        ((float2*)out)[(size_t)node * 16 + f2] = o;
    }
}

// ---------------- launch ----------------

extern "C" void kernel_launch(void* const* d_in, const int* in_sizes, int n_in,
                              void* d_out, int out_size, void* d_ws, size_t ws_size,
                              hipStream_t stream) {
    const float* x    = (const float*)d_in[0];
    const int* esrc   = (const int*)d_in[1];
    const int* edst   = (const int*)d_in[2];
    const float* ev   = (const float*)d_in[3];
    const float* W1   = (const float*)d_in[4];
    const float* W2   = (const float*)d_in[5];
    float* out        = (float*)d_out;

    // workspace layout; pre2b aliases pre1b (pre1b dead after spmm1)
    unsigned short* pre1b = (unsigned short*)d_ws;            // 6,400,000 ushort (12.8 MB)
    unsigned* hb          = (unsigned*)(pre1b + 6400000);     // 3,200,000 uint (12.8 MB)
    unsigned short* pre2b = pre1b;                            // 1,600,000 ushort (alias)
    unsigned long long* csr_ev = (unsigned long long*)(hb + 3200000);  // 800,000 x 8B (6.4 MB)
    int* row_ptr          = (int*)(csr_ev + 800000);          // 50,001 (pad 50,048)
    int* cursor           = row_ptr + 50048;
    int* bsum             = cursor + 50048;
    int* boff             = bsum + 256;
    unsigned short* W1t   = (unsigned short*)(boff + 256);    // 65,536 ushort

    hipLaunchKernelGGL(zero_k,     dim3(196),  dim3(256), 0, stream, cursor);
    hipLaunchKernelGGL(hist_k,     dim3(3125), dim3(256), 0, stream, esrc, cursor);
    hipLaunchKernelGGL(w1conv_k,   dim3(256),  dim3(256), 0, stream, W1, W1t);
    hipLaunchKernelGGL(scan_a,     dim3(196),  dim3(256), 0, stream, cursor, bsum);
    hipLaunchKernelGGL(scan_b,     dim3(1),    dim3(256), 0, stream, bsum, boff);
    hipLaunchKernelGGL(scan_c,     dim3(196),  dim3(256), 0, stream, cursor, boff, row_ptr, cursor);
    hipLaunchKernelGGL(scatter_k,  dim3(3125), dim3(256), 0, stream, esrc, edst, ev, cursor, csr_ev);

    hipLaunchKernelGGL(gemm1_mfma, dim3(782),  dim3(256), 0, stream, x, W1t, pre1b);
    hipLaunchKernelGGL(spmm1_k,    dim3(12500),dim3(256), 0, stream, row_ptr, csr_ev, (const unsigned*)pre1b, hb);
    hipLaunchKernelGGL(gemm2_k,    dim3(1563), dim3(256), 0, stream, hb, W2, pre2b);
    hipLaunchKernelGGL(spmm2_k,    dim3(12500),dim3(256), 0, stream, row_ptr, csr_ev, (const unsigned*)pre2b, out);
}

// Round 6
// 157.373 us; speedup vs baseline: 1.5188x; 1.5188x over previous
//
#include <hip/hip_runtime.h>
#include <hip/hip_bf16.h>

#define N_NODES 50000
#define N_EDGES 800000
#define N_FEAT 512
#define HIDDEN 128
#define N_CLASSES 32

#define NBUCK 196        // coarse buckets: src>>8 (256-node regions)
#define REG_STRIDE 6144  // slots per region (mean 4081, sigma 64 -> 30+ sigma headroom)

typedef __attribute__((ext_vector_type(8))) short bf16x8;
typedef __attribute__((ext_vector_type(4))) float f32x4;

// round-to-nearest-even f32 -> bf16 bits
static __device__ __forceinline__ unsigned short f2bf(float f) {
    unsigned u = __float_as_uint(f);
    u += 0x7FFFu + ((u >> 16) & 1u);
    return (unsigned short)(u >> 16);
}
// unpack uint = (bf16_hi<<16)|bf16_lo
static __device__ __forceinline__ float bflo(unsigned u) { return __uint_as_float(u << 16); }
static __device__ __forceinline__ float bfhi(unsigned u) { return __uint_as_float(u & 0xFFFF0000u); }
static __device__ __forceinline__ unsigned pack2(float a, float b) {
    return (unsigned)f2bf(a) | ((unsigned)f2bf(b) << 16);
}

// ---------------- util ----------------

__global__ __launch_bounds__(256) void zero_k(int* __restrict__ p, int n) {
    int i = blockIdx.x * 256 + threadIdx.x;
    if (i < n) p[i] = 0;
}

// ---------------- CSR build, phase 1: LDS-bucketed coarse scatter ----------------
// record: src(16) | dst(16)<<16 | val_bits<<32

__global__ __launch_bounds__(256) void bucket1_k(const int* __restrict__ src, const int* __restrict__ dst,
                                                 const float* __restrict__ val,
                                                 int* __restrict__ gcursor,
                                                 unsigned long long* __restrict__ tmp) {
    __shared__ int cnt[256];
    __shared__ int lstart[256];
    __shared__ int lcur[256];
    __shared__ int gbase[256];
    __shared__ unsigned long long buf[2048];   // 16 KB
    const int t = threadIdx.x;
    const int e0 = blockIdx.x * 2048;
    const int ne = min(2048, N_EDGES - e0);

    cnt[t] = 0;
    __syncthreads();

    unsigned long long rec[8];
    int rb[8];
#pragma unroll
    for (int j = 0; j < 8; ++j) {
        int p = j * 256 + t;
        rec[j] = 0; rb[j] = -1;
        if (p < ne) {
            int i = e0 + p;
            unsigned s = (unsigned)src[i];
            rec[j] = (unsigned long long)(s | ((unsigned)dst[i] << 16))
                   | ((unsigned long long)__float_as_uint(val[i]) << 32);
            int b = (int)(s >> 8);
            rb[j] = b;
            atomicAdd(&cnt[b], 1);
        }
    }
    __syncthreads();
    const int cv = cnt[t];
    // inclusive scan (Hillis-Steele)
    for (int off = 1; off < 256; off <<= 1) {
        int xv = (t >= off) ? cnt[t - off] : 0;
        __syncthreads();
        cnt[t] += xv;
        __syncthreads();
    }
    lstart[t] = cnt[t] - cv;
    lcur[t]   = cnt[t] - cv;
    if (t < NBUCK) gbase[t] = atomicAdd(&gcursor[t], cv);
    __syncthreads();
    // place records bucket-grouped into LDS
#pragma unroll
    for (int j = 0; j < 8; ++j) {
        if (rb[j] >= 0) {
            int pos = atomicAdd(&lcur[rb[j]], 1);
            buf[pos] = rec[j];
        }
    }
    __syncthreads();
    // burst write-out: consecutive p within a bucket -> consecutive global slots
#pragma unroll
    for (int j = 0; j < 8; ++j) {
        int p = j * 256 + t;
        if (p < ne) {
            unsigned long long r = buf[p];
            int b = (int)((r & 0xFFFFu) >> 8);
            int tgt = gbase[b] + (p - lstart[b]);
            tmp[(size_t)b * REG_STRIDE + tgt] = r;
        }
    }
}

// ---------------- CSR build, phase 2: per-region local sort + row_ptr ----------------

__global__ __launch_bounds__(256) void bucket2_k(const int* __restrict__ gcursor,
                                                 const unsigned long long* __restrict__ tmp,
                                                 unsigned long long* __restrict__ csr_ev,
                                                 int* __restrict__ row_ptr) {
    __shared__ int lcnt[256];
    __shared__ int lcur[256];
    __shared__ int cnts[NBUCK];
    __shared__ int base_s;
    const int b = blockIdx.x;
    const int t = threadIdx.x;
    if (t < NBUCK) cnts[t] = gcursor[t];
    lcnt[t] = 0;
    __syncthreads();
    const int nb = cnts[b];
    if (t == 0) {
        int s = 0;
        for (int r = 0; r < b; ++r) s += cnts[r];
        base_s = s;
    }
    const unsigned long long* reg = tmp + (size_t)b * REG_STRIDE;
    __syncthreads();
    // pass 1: per-node counts (local node = rec & 255, regions are 256-aligned)
    for (int p = t; p < nb; p += 256)
        atomicAdd(&lcnt[(int)(reg[p] & 0xFFu)], 1);
    __syncthreads();
    const int cv = lcnt[t];
    for (int off = 1; off < 256; off <<= 1) {
        int xv = (t >= off) ? lcnt[t - off] : 0;
        __syncthreads();
        lcnt[t] += xv;
        __syncthreads();
    }
    const int abs_start = base_s + lcnt[t] - cv;
    lcur[t] = abs_start;
    int node = b * 256 + t;
    if (node <= N_NODES) row_ptr[node] = abs_start;
    __syncthreads();
    // pass 2: place (L2-hot ~33KB window)
    for (int p = t; p < nb; p += 256) {
        unsigned long long r = reg[p];
        int pos = atomicAdd(&lcur[(int)(r & 0xFFu)], 1);
        csr_ev[pos] = ((r >> 16) & 0xFFFFull) | (r & 0xFFFFFFFF00000000ull);
    }
}

// ---------------- W1 transpose + bf16: W1[512][128] -> W1t[128][512] bf16 ----------------

__global__ __launch_bounds__(256) void w1conv_k(const float* __restrict__ W1,
                                                unsigned short* __restrict__ W1t) {
    int id = blockIdx.x * 256 + threadIdx.x;   // 65536
    int c = id >> 9;          // 0..127
    int k = id & 511;         // 0..511
    W1t[(size_t)c * N_FEAT + k] = f2bf(W1[(size_t)k * HIDDEN + c]);
}

// ---------------- GEMM1 via bf16 MFMA: pre1b = bf16(x @ W1) ----------------
// 64x128 tile, grid 782 (~3 blocks/CU), 4 waves: wave w -> cols w*32..w*32+31.

#define LDT 72   // shorts per LDS row (64 + 8 pad -> 144B stride, 2-way conflicts = free)

__global__ __launch_bounds__(256, 4) void gemm1_mfma(const float* __restrict__ x,
                                                     const unsigned short* __restrict__ W1t,
                                                     unsigned short* __restrict__ pre1b) {
    __shared__ short As[64 * LDT];     // 9.2 KB
    __shared__ short Bs[128 * LDT];    // 18.4 KB

    const int t = threadIdx.x;
    const int w = t >> 6;        // 0..3: col quarter
    const int l = t & 63;
    const int row0 = blockIdx.x * 64;
    const int l15 = l & 15;
    const int lhi = l >> 4;

    f32x4 acc[4][2];
#pragma unroll
    for (int m = 0; m < 4; ++m)
#pragma unroll
        for (int n = 0; n < 2; ++n) acc[m][n] = (f32x4){0.f, 0.f, 0.f, 0.f};

    for (int k0 = 0; k0 < N_FEAT; k0 += 64) {
        __syncthreads();
        // stage x tile 64x64 f32 -> bf16 (4 float4 per thread)
#pragma unroll
        for (int j = 0; j < 4; ++j) {
            int f = j * 256 + t;
            int ar = f >> 4;              // 0..63
            int ak = (f & 15) << 2;       // 0..60
            int gr = row0 + ar;
            if (gr > N_NODES - 1) gr = N_NODES - 1;
            float4 v = *(const float4*)(x + (size_t)gr * N_FEAT + k0 + ak);
            ushort4 hh;
            hh.x = f2bf(v.x); hh.y = f2bf(v.y); hh.z = f2bf(v.z); hh.w = f2bf(v.w);
            *(ushort4*)&As[ar * LDT + ak] = hh;
        }
        // stage W1t tile 128x64 bf16 (4 x 16B per thread)
#pragma unroll
        for (int j = 0; j < 4; ++j) {
            int f = j * 256 + t;
            int br = f >> 3;              // 0..127 (col index)
            int bk = (f & 7) << 3;        // 0..56 shorts
            *(bf16x8*)&Bs[br * LDT + bk] = *(const bf16x8*)(W1t + (size_t)br * N_FEAT + k0 + bk);
        }
        __syncthreads();
#pragma unroll
        for (int ks = 0; ks < 2; ++ks) {
            const int koff = ks * 32 + lhi * 8;
            bf16x8 af[4], bf[2];
#pragma unroll
            for (int m = 0; m < 4; ++m)
                af[m] = *(bf16x8*)&As[(m * 16 + l15) * LDT + koff];
#pragma unroll
            for (int n = 0; n < 2; ++n)
                bf[n] = *(bf16x8*)&Bs[(w * 32 + n * 16 + l15) * LDT + koff];
#pragma unroll
            for (int m = 0; m < 4; ++m)
#pragma unroll
                for (int n = 0; n < 2; ++n)
                    acc[m][n] = __builtin_amdgcn_mfma_f32_16x16x32_bf16(af[m], bf[n], acc[m][n], 0, 0, 0);
        }
    }
    // epilogue: C/D layout col=lane&15, row=(lane>>4)*4+reg ; write bf16
    const int c0 = w * 32;
#pragma unroll
    for (int m = 0; m < 4; ++m)
#pragma unroll
        for (int n = 0; n < 2; ++n) {
#pragma unroll
            for (int j = 0; j < 4; ++j) {
                int r = row0 + m * 16 + lhi * 4 + j;
                if (r < N_NODES) pre1b[(size_t)r * HIDDEN + c0 + n * 16 + l15] = f2bf(acc[m][n][j]);
            }
        }
}

// ---------------- SpMM1: hb = bf16(relu(A @ pre1)), one wave per node, 1 uint (2 feats)/lane ----------------

__global__ __launch_bounds__(256) void spmm1_k(const int* __restrict__ rp,
                                               const unsigned long long* __restrict__ ce,
                                               const unsigned* __restrict__ P,
                                               unsigned* __restrict__ hb) {
    const int g = threadIdx.x >> 6;
    const int lane = threadIdx.x & 63;
    const int node = blockIdx.x * 4 + g;
    if (node >= N_NODES) return;
    const int s = rp[node], e = rp[node + 1];
    float2 a0; a0.x = 0.f; a0.y = 0.f;
    float2 a1; a1.x = 0.f; a1.y = 0.f;
    int i = s;
    for (; i + 2 <= e; i += 2) {
        unsigned long long e0 = ce[i], e1 = ce[i + 1];
        int d0 = (int)(unsigned)e0, d1 = (int)(unsigned)e1;
        float v0 = __uint_as_float((unsigned)(e0 >> 32));
        float v1 = __uint_as_float((unsigned)(e1 >> 32));
        unsigned u0 = P[(size_t)d0 * 64 + lane];
        unsigned u1 = P[(size_t)d1 * 64 + lane];
        a0.x += v0 * bflo(u0); a0.y += v0 * bfhi(u0);
        a1.x += v1 * bflo(u1); a1.y += v1 * bfhi(u1);
    }
    if (i < e) {
        unsigned long long e0 = ce[i];
        int d0 = (int)(unsigned)e0;
        float v0 = __uint_as_float((unsigned)(e0 >> 32));
        unsigned u0 = P[(size_t)d0 * 64 + lane];
        a0.x += v0 * bflo(u0); a0.y += v0 * bfhi(u0);
    }
    a0.x += a1.x; a0.y += a1.y;
    a0.x = a0.x > 0.f ? a0.x : 0.f;
    a0.y = a0.y > 0.f ? a0.y : 0.f;
    hb[(size_t)node * 64 + lane] = pack2(a0.x, a0.y);
}

// ---------------- GEMM2: pre2b[50000,32] = bf16(h @ W2) ----------------

__global__ __launch_bounds__(256) void gemm2_k(const unsigned* __restrict__ hb,
                                               const float* __restrict__ W2,
                                               unsigned short* __restrict__ pre2b) {
    __shared__ float hs[32][132];
    __shared__ float w2s[HIDDEN][N_CLASSES];
    const int t = threadIdx.x;
    const int row0 = blockIdx.x * 32;
#pragma unroll
    for (int j = 0; j < 4; ++j) {        // W2: 1024 float4
        int f = j * 256 + t;
        int r = f >> 3;
        int c = (f & 7) << 2;
        *(float4*)&w2s[r][c] = *(const float4*)(W2 + (size_t)r * N_CLASSES + c);
    }
#pragma unroll
    for (int j = 0; j < 2; ++j) {        // h tile: 32 rows x 64 uints = 2048 uints
        int f = j * 256 + t;
        int r = f >> 4;                  // 0..31
        int cu = (f & 15) << 2;          // uint col 0..60 step 4
        int grr = row0 + r;
        if (grr >= N_NODES) grr = N_NODES - 1;
        uint4 u = *(const uint4*)(hb + (size_t)grr * 64 + cu);
        hs[r][2 * cu + 0] = bflo(u.x); hs[r][2 * cu + 1] = bfhi(u.x);
        hs[r][2 * cu + 2] = bflo(u.y); hs[r][2 * cu + 3] = bfhi(u.y);
        hs[r][2 * cu + 4] = bflo(u.z); hs[r][2 * cu + 5] = bfhi(u.z);
        hs[r][2 * cu + 6] = bflo(u.w); hs[r][2 * cu + 7] = bfhi(u.w);
    }
    __syncthreads();
    const int r = t >> 3;
    const int c = (t & 7) << 2;
    float4 acc; acc.x = acc.y = acc.z = acc.w = 0.f;
#pragma unroll 16
    for (int kk = 0; kk < HIDDEN; ++kk) {
        float a = hs[r][kk];
        float4 b = *(const float4*)&w2s[kk][c];
        acc.x += a * b.x; acc.y += a * b.y; acc.z += a * b.z; acc.w += a * b.w;
    }
    int grr = row0 + r;
    if (grr < N_NODES) {
        uint2 o;
        o.x = pack2(acc.x, acc.y);
        o.y = pack2(acc.z, acc.w);
        *(uint2*)&pre2b[(size_t)grr * N_CLASSES + c] = o;
    }
}

// ---------------- SpMM2: out = A @ pre2 ; 16 lanes/edge, 4 edges/iter ----------------

__global__ __launch_bounds__(256) void spmm2_k(const int* __restrict__ rp,
                                               const unsigned long long* __restrict__ ce,
                                               const unsigned* __restrict__ P2,
                                               float* __restrict__ out) {
    const int g = threadIdx.x >> 6;
    const int lane = threadIdx.x & 63;
    const int node = blockIdx.x * 4 + g;
    if (node >= N_NODES) return;
    const int s = rp[node], e = rp[node + 1];
    const int f2 = lane & 15;      // uint index: feats 2*f2, 2*f2+1
    const int par = lane >> 4;     // 0..3
    float ax = 0.f, ay = 0.f;
    for (int i = s + par; i < e; i += 4) {
        unsigned long long ed = ce[i];
        int dst = (int)(unsigned)ed;
        float v = __uint_as_float((unsigned)(ed >> 32));
        unsigned u = P2[(size_t)dst * 16 + f2];
        ax += v * bflo(u);
        ay += v * bfhi(u);
    }
    ax += __shfl_xor(ax, 16); ay += __shfl_xor(ay, 16);
    ax += __shfl_xor(ax, 32); ay += __shfl_xor(ay, 32);
    if (lane < 16) {
        float2 o; o.x = ax; o.y = ay;
        ((float2*)out)[(size_t)node * 16 + f2] = o;
    }
}

// ---------------- launch ----------------

extern "C" void kernel_launch(void* const* d_in, const int* in_sizes, int n_in,
                              void* d_out, int out_size, void* d_ws, size_t ws_size,
                              hipStream_t stream) {
    const float* x    = (const float*)d_in[0];
    const int* esrc   = (const int*)d_in[1];
    const int* edst   = (const int*)d_in[2];
    const float* ev   = (const float*)d_in[3];
    const float* W1   = (const float*)d_in[4];
    const float* W2   = (const float*)d_in[5];
    float* out        = (float*)d_out;

    // workspace layout; pre2b aliases pre1b (pre1b dead after spmm1)
    unsigned short* pre1b = (unsigned short*)d_ws;            // 6,400,000 ushort (12.8 MB)
    unsigned* hb          = (unsigned*)(pre1b + 6400000);     // 3,200,000 uint (12.8 MB)
    unsigned short* pre2b = pre1b;                            // alias
    unsigned long long* csr_ev = (unsigned long long*)(hb + 3200000);   // 800,000 u64 (6.4 MB)
    unsigned long long* tmp    = csr_ev + 800000;             // 196*6144 u64 (9.63 MB)
    int* row_ptr          = (int*)(tmp + (size_t)NBUCK * REG_STRIDE);   // 50,001 (pad 50,048)
    int* gcursor          = row_ptr + 50048;                  // 256
    unsigned short* W1t   = (unsigned short*)(gcursor + 256); // 65,536 ushort

    hipLaunchKernelGGL(zero_k,     dim3(1),    dim3(256), 0, stream, gcursor, NBUCK);
    hipLaunchKernelGGL(w1conv_k,   dim3(256),  dim3(256), 0, stream, W1, W1t);
    hipLaunchKernelGGL(bucket1_k,  dim3(391),  dim3(256), 0, stream, esrc, edst, ev, gcursor, tmp);
    hipLaunchKernelGGL(bucket2_k,  dim3(NBUCK),dim3(256), 0, stream, gcursor, tmp, csr_ev, row_ptr);

    hipLaunchKernelGGL(gemm1_mfma, dim3(782),  dim3(256), 0, stream, x, W1t, pre1b);
    hipLaunchKernelGGL(spmm1_k,    dim3(12500),dim3(256), 0, stream, row_ptr, csr_ev, (const unsigned*)pre1b, hb);
    hipLaunchKernelGGL(gemm2_k,    dim3(1563), dim3(256), 0, stream, hb, W2, pre2b);
    hipLaunchKernelGGL(spmm2_k,    dim3(12500),dim3(256), 0, stream, row_ptr, csr_ev, (const unsigned*)pre2b, out);
}

// Round 7
// 155.097 us; speedup vs baseline: 1.5411x; 1.0147x over previous
//
#include <hip/hip_runtime.h>
#include <hip/hip_bf16.h>

#define N_NODES 50000
#define N_EDGES 800000
#define N_FEAT 512
#define HIDDEN 128
#define N_CLASSES 32

#define NBUCK 196        // coarse buckets: src>>8 (256-node regions)
#define REG_STRIDE 6144  // slots per region (mean 4081, sigma 64 -> 30+ sigma headroom)

typedef __attribute__((ext_vector_type(8))) short bf16x8;
typedef __attribute__((ext_vector_type(4))) float f32x4;

// round-to-nearest-even f32 -> bf16 bits
static __device__ __forceinline__ unsigned short f2bf(float f) {
    unsigned u = __float_as_uint(f);
    u += 0x7FFFu + ((u >> 16) & 1u);
    return (unsigned short)(u >> 16);
}
// unpack uint = (bf16_hi<<16)|bf16_lo
static __device__ __forceinline__ float bflo(unsigned u) { return __uint_as_float(u << 16); }
static __device__ __forceinline__ float bfhi(unsigned u) { return __uint_as_float(u & 0xFFFF0000u); }
static __device__ __forceinline__ unsigned pack2(float a, float b) {
    return (unsigned)f2bf(a) | ((unsigned)f2bf(b) << 16);
}

// ---------------- CSR build, phase 1: LDS-bucketed coarse scatter ----------------
// record: src(16) | dst(16)<<16 | val_bits<<32

__global__ __launch_bounds__(256) void bucket1_k(const int* __restrict__ src, const int* __restrict__ dst,
                                                 const float* __restrict__ val,
                                                 int* __restrict__ gcursor,
                                                 unsigned long long* __restrict__ tmp) {
    __shared__ int cnt[256];
    __shared__ int lstart[256];
    __shared__ int lcur[256];
    __shared__ int gbase[256];
    __shared__ unsigned long long buf[2048];   // 16 KB
    const int t = threadIdx.x;
    const int e0 = blockIdx.x * 2048;
    const int ne = min(2048, N_EDGES - e0);

    cnt[t] = 0;
    __syncthreads();

    unsigned long long rec[8];
    int rb[8];
#pragma unroll
    for (int j = 0; j < 8; ++j) {
        int p = j * 256 + t;
        rec[j] = 0; rb[j] = -1;
        if (p < ne) {
            int i = e0 + p;
            unsigned s = (unsigned)src[i];
            rec[j] = (unsigned long long)(s | ((unsigned)dst[i] << 16))
                   | ((unsigned long long)__float_as_uint(val[i]) << 32);
            int b = (int)(s >> 8);
            rb[j] = b;
            atomicAdd(&cnt[b], 1);
        }
    }
    __syncthreads();
    const int cv = cnt[t];
    // inclusive scan (Hillis-Steele)
    for (int off = 1; off < 256; off <<= 1) {
        int xv = (t >= off) ? cnt[t - off] : 0;
        __syncthreads();
        cnt[t] += xv;
        __syncthreads();
    }
    lstart[t] = cnt[t] - cv;
    lcur[t]   = cnt[t] - cv;
    if (t < NBUCK) gbase[t] = atomicAdd(&gcursor[t], cv);
    __syncthreads();
    // place records bucket-grouped into LDS
#pragma unroll
    for (int j = 0; j < 8; ++j) {
        if (rb[j] >= 0) {
            int pos = atomicAdd(&lcur[rb[j]], 1);
            buf[pos] = rec[j];
        }
    }
    __syncthreads();
    // burst write-out: consecutive p within a bucket -> consecutive global slots
#pragma unroll
    for (int j = 0; j < 8; ++j) {
        int p = j * 256 + t;
        if (p < ne) {
            unsigned long long r = buf[p];
            int b = (int)((r & 0xFFFFu) >> 8);
            int tgt = gbase[b] + (p - lstart[b]);
            tmp[(size_t)b * REG_STRIDE + tgt] = r;
        }
    }
}

// ---------------- CSR build, phase 2: per-region local sort + row_ptr ----------------

__global__ __launch_bounds__(256) void bucket2_k(const int* __restrict__ gcursor,
                                                 const unsigned long long* __restrict__ tmp,
                                                 unsigned long long* __restrict__ csr_ev,
                                                 int* __restrict__ row_ptr) {
    __shared__ int lcnt[256];
    __shared__ int lcur[256];
    __shared__ int cnts[NBUCK];
    __shared__ int base_s;
    const int b = blockIdx.x;
    const int t = threadIdx.x;
    if (t < NBUCK) cnts[t] = gcursor[t];
    lcnt[t] = 0;
    __syncthreads();
    const int nb = cnts[b];
    if (t == 0) {
        int s = 0;
        for (int r = 0; r < b; ++r) s += cnts[r];
        base_s = s;
    }
    const unsigned long long* reg = tmp + (size_t)b * REG_STRIDE;
    __syncthreads();
    // pass 1: per-node counts (local node = rec & 255, regions are 256-aligned)
    for (int p = t; p < nb; p += 256)
        atomicAdd(&lcnt[(int)(reg[p] & 0xFFu)], 1);
    __syncthreads();
    const int cv = lcnt[t];
    for (int off = 1; off < 256; off <<= 1) {
        int xv = (t >= off) ? lcnt[t - off] : 0;
        __syncthreads();
        lcnt[t] += xv;
        __syncthreads();
    }
    const int abs_start = base_s + lcnt[t] - cv;
    lcur[t] = abs_start;
    int node = b * 256 + t;
    if (node <= N_NODES) row_ptr[node] = abs_start;
    __syncthreads();
    // pass 2: place (L2-hot ~33KB window)
    for (int p = t; p < nb; p += 256) {
        unsigned long long r = reg[p];
        int pos = atomicAdd(&lcur[(int)(r & 0xFFu)], 1);
        csr_ev[pos] = ((r >> 16) & 0xFFFFull) | (r & 0xFFFFFFFF00000000ull);
    }
}

// ---------------- W1 transpose + bf16 (+ gcursor zero): W1[512][128] -> W1t[128][512] ----------------

__global__ __launch_bounds__(256) void w1conv_k(const float* __restrict__ W1,
                                                unsigned short* __restrict__ W1t,
                                                int* __restrict__ gcursor) {
    if (blockIdx.x == 0 && threadIdx.x < NBUCK) gcursor[threadIdx.x] = 0;
    int id = blockIdx.x * 256 + threadIdx.x;   // 65536
    int c = id >> 9;          // 0..127
    int k = id & 511;         // 0..511
    W1t[(size_t)c * N_FEAT + k] = f2bf(W1[(size_t)k * HIDDEN + c]);
}

// ---------------- GEMM1 via bf16 MFMA, 2-phase pipeline ----------------
// 64x128 tile, 4 waves (wave w -> cols w*32..w*32+31), BK=64, 8 K-iters.
// A: LDS double-buffered, reg-staged (issue loads after barrier, write after MFMA).
// B: direct 16B global loads from L2-hot W1t (128 KB), no LDS.
// ONE barrier per iteration.

#define LDT 72   // shorts per LDS row (64 + 8 pad)

__global__ __launch_bounds__(256, 4) void gemm1_mfma(const float* __restrict__ x,
                                                     const unsigned short* __restrict__ W1t,
                                                     unsigned short* __restrict__ pre1b) {
    __shared__ short As[2][64 * LDT];   // 2 x 9.2 KB

    const int t = threadIdx.x;
    const int w = t >> 6;        // 0..3: col quarter
    const int l = t & 63;
    const int row0 = blockIdx.x * 64;
    const int l15 = l & 15;
    const int lhi = l >> 4;

    // A staging: thread t loads row lr, float cols lk..lk+15 (4 float4)
    const int lr = t >> 2;            // 0..63
    const int lk = (t & 3) << 4;      // 0,16,32,48
    int gr = row0 + lr;
    if (gr > N_NODES - 1) gr = N_NODES - 1;   // clamp (epilogue writes are guarded)
    const float* xrow = x + (size_t)gr * N_FEAT + lk;

    // B row pointers for this lane's fragments
    const unsigned short* b0 = W1t + (size_t)(w * 32 + l15) * N_FEAT;
    const unsigned short* b1 = W1t + (size_t)(w * 32 + 16 + l15) * N_FEAT;

    f32x4 acc[4][2];
#pragma unroll
    for (int m = 0; m < 4; ++m)
#pragma unroll
        for (int n = 0; n < 2; ++n) acc[m][n] = (f32x4){0.f, 0.f, 0.f, 0.f};

    // prologue: stage tile 0 into buf 0
    {
        float4 ld[4];
#pragma unroll
        for (int j = 0; j < 4; ++j) ld[j] = *(const float4*)(xrow + 4 * j);
#pragma unroll
        for (int j = 0; j < 4; ++j) {
            ushort4 hh;
            hh.x = f2bf(ld[j].x); hh.y = f2bf(ld[j].y); hh.z = f2bf(ld[j].z); hh.w = f2bf(ld[j].w);
            *(ushort4*)&As[0][lr * LDT + lk + 4 * j] = hh;
        }
    }

    int cur = 0;
    for (int k0 = 0; k0 < N_FEAT; k0 += 64) {
        __syncthreads();                       // As[cur] ready for all waves
        const bool hasnext = (k0 + 64 < N_FEAT);
        // issue next A tile loads immediately (fly under compute)
        float4 ld[4];
        if (hasnext) {
#pragma unroll
            for (int j = 0; j < 4; ++j) ld[j] = *(const float4*)(xrow + k0 + 64 + 4 * j);
        }
        // B fragments for this K-chunk: 4 x 16B (L2-hot)
        bf16x8 bfr[2][2];
#pragma unroll
        for (int ks = 0; ks < 2; ++ks) {
            const int koff = k0 + ks * 32 + lhi * 8;
            bfr[ks][0] = *(const bf16x8*)(b0 + koff);
            bfr[ks][1] = *(const bf16x8*)(b1 + koff);
        }
        // MFMA on As[cur]
#pragma unroll
        for (int ks = 0; ks < 2; ++ks) {
            const int koff = ks * 32 + lhi * 8;
            bf16x8 af[4];
#pragma unroll
            for (int m = 0; m < 4; ++m)
                af[m] = *(bf16x8*)&As[cur][(m * 16 + l15) * LDT + koff];
#pragma unroll
            for (int m = 0; m < 4; ++m) {
                acc[m][0] = __builtin_amdgcn_mfma_f32_16x16x32_bf16(af[m], bfr[ks][0], acc[m][0], 0, 0, 0);
                acc[m][1] = __builtin_amdgcn_mfma_f32_16x16x32_bf16(af[m], bfr[ks][1], acc[m][1], 0, 0, 0);
            }
        }
        // convert + write next tile into the other buffer (no reader of it in this window)
        if (hasnext) {
#pragma unroll
            for (int j = 0; j < 4; ++j) {
                ushort4 hh;
                hh.x = f2bf(ld[j].x); hh.y = f2bf(ld[j].y); hh.z = f2bf(ld[j].z); hh.w = f2bf(ld[j].w);
                *(ushort4*)&As[cur ^ 1][lr * LDT + lk + 4 * j] = hh;
            }
        }
        cur ^= 1;
    }
    // epilogue: C/D layout col=lane&15, row=(lane>>4)*4+reg ; write bf16
    const int c0 = w * 32;
#pragma unroll
    for (int m = 0; m < 4; ++m)
#pragma unroll
        for (int n = 0; n < 2; ++n) {
#pragma unroll
            for (int j = 0; j < 4; ++j) {
                int r = row0 + m * 16 + lhi * 4 + j;
                if (r < N_NODES) pre1b[(size_t)r * HIDDEN + c0 + n * 16 + l15] = f2bf(acc[m][n][j]);
            }
        }
}

// ---------------- SpMM1: hb = bf16(relu(A @ pre1)), one wave per node, 1 uint (2 feats)/lane ----------------

__global__ __launch_bounds__(256) void spmm1_k(const int* __restrict__ rp,
                                               const unsigned long long* __restrict__ ce,
                                               const unsigned* __restrict__ P,
                                               unsigned* __restrict__ hb) {
    const int g = threadIdx.x >> 6;
    const int lane = threadIdx.x & 63;
    const int node = blockIdx.x * 4 + g;
    if (node >= N_NODES) return;
    const int s = rp[node], e = rp[node + 1];
    float2 a0; a0.x = 0.f; a0.y = 0.f;
    float2 a1; a1.x = 0.f; a1.y = 0.f;
    int i = s;
    for (; i + 2 <= e; i += 2) {
        unsigned long long e0 = ce[i], e1 = ce[i + 1];
        int d0 = (int)(unsigned)e0, d1 = (int)(unsigned)e1;
        float v0 = __uint_as_float((unsigned)(e0 >> 32));
        float v1 = __uint_as_float((unsigned)(e1 >> 32));
        unsigned u0 = P[(size_t)d0 * 64 + lane];
        unsigned u1 = P[(size_t)d1 * 64 + lane];
        a0.x += v0 * bflo(u0); a0.y += v0 * bfhi(u0);
        a1.x += v1 * bflo(u1); a1.y += v1 * bfhi(u1);
    }
    if (i < e) {
        unsigned long long e0 = ce[i];
        int d0 = (int)(unsigned)e0;
        float v0 = __uint_as_float((unsigned)(e0 >> 32));
        unsigned u0 = P[(size_t)d0 * 64 + lane];
        a0.x += v0 * bflo(u0); a0.y += v0 * bfhi(u0);
    }
    a0.x += a1.x; a0.y += a1.y;
    a0.x = a0.x > 0.f ? a0.x : 0.f;
    a0.y = a0.y > 0.f ? a0.y : 0.f;
    hb[(size_t)node * 64 + lane] = pack2(a0.x, a0.y);
}

// ---------------- GEMM2: pre2b[50000,32] = bf16(h @ W2) ----------------

__global__ __launch_bounds__(256) void gemm2_k(const unsigned* __restrict__ hb,
                                               const float* __restrict__ W2,
                                               unsigned short* __restrict__ pre2b) {
    __shared__ float hs[32][132];
    __shared__ float w2s[HIDDEN][N_CLASSES];
    const int t = threadIdx.x;
    const int row0 = blockIdx.x * 32;
#pragma unroll
    for (int j = 0; j < 4; ++j) {        // W2: 1024 float4
        int f = j * 256 + t;
        int r = f >> 3;
        int c = (f & 7) << 2;
        *(float4*)&w2s[r][c] = *(const float4*)(W2 + (size_t)r * N_CLASSES + c);
    }
#pragma unroll
    for (int j = 0; j < 2; ++j) {        // h tile: 32 rows x 64 uints = 2048 uints
        int f = j * 256 + t;
        int r = f >> 4;                  // 0..31
        int cu = (f & 15) << 2;          // uint col 0..60 step 4
        int grr = row0 + r;
        if (grr >= N_NODES) grr = N_NODES - 1;
        uint4 u = *(const uint4*)(hb + (size_t)grr * 64 + cu);
        hs[r][2 * cu + 0] = bflo(u.x); hs[r][2 * cu + 1] = bfhi(u.x);
        hs[r][2 * cu + 2] = bflo(u.y); hs[r][2 * cu + 3] = bfhi(u.y);
        hs[r][2 * cu + 4] = bflo(u.z); hs[r][2 * cu + 5] = bfhi(u.z);
        hs[r][2 * cu + 6] = bflo(u.w); hs[r][2 * cu + 7] = bfhi(u.w);
    }
    __syncthreads();
    const int r = t >> 3;
    const int c = (t & 7) << 2;
    float4 acc; acc.x = acc.y = acc.z = acc.w = 0.f;
#pragma unroll 16
    for (int kk = 0; kk < HIDDEN; ++kk) {
        float a = hs[r][kk];
        float4 b = *(const float4*)&w2s[kk][c];
        acc.x += a * b.x; acc.y += a * b.y; acc.z += a * b.z; acc.w += a * b.w;
    }
    int grr = row0 + r;
    if (grr < N_NODES) {
        uint2 o;
        o.x = pack2(acc.x, acc.y);
        o.y = pack2(acc.z, acc.w);
        *(uint2*)&pre2b[(size_t)grr * N_CLASSES + c] = o;
    }
}

// ---------------- SpMM2: out = A @ pre2 ; 16 lanes/edge, 4 edges/iter ----------------

__global__ __launch_bounds__(256) void spmm2_k(const int* __restrict__ rp,
                                               const unsigned long long* __restrict__ ce,
                                               const unsigned* __restrict__ P2,
                                               float* __restrict__ out) {
    const int g = threadIdx.x >> 6;
    const int lane = threadIdx.x & 63;
    const int node = blockIdx.x * 4 + g;
    if (node >= N_NODES) return;
    const int s = rp[node], e = rp[node + 1];
    const int f2 = lane & 15;      // uint index: feats 2*f2, 2*f2+1
    const int par = lane >> 4;     // 0..3
    float ax = 0.f, ay = 0.f;
    for (int i = s + par; i < e; i += 4) {
        unsigned long long ed = ce[i];
        int dst = (int)(unsigned)ed;
        float v = __uint_as_float((unsigned)(ed >> 32));
        unsigned u = P2[(size_t)dst * 16 + f2];
        ax += v * bflo(u);
        ay += v * bfhi(u);
    }
    ax += __shfl_xor(ax, 16); ay += __shfl_xor(ay, 16);
    ax += __shfl_xor(ax, 32); ay += __shfl_xor(ay, 32);
    if (lane < 16) {
        float2 o; o.x = ax; o.y = ay;
        ((float2*)out)[(size_t)node * 16 + f2] = o;
    }
}

// ---------------- launch ----------------

extern "C" void kernel_launch(void* const* d_in, const int* in_sizes, int n_in,
                              void* d_out, int out_size, void* d_ws, size_t ws_size,
                              hipStream_t stream) {
    const float* x    = (const float*)d_in[0];
    const int* esrc   = (const int*)d_in[1];
    const int* edst   = (const int*)d_in[2];
    const float* ev   = (const float*)d_in[3];
    const float* W1   = (const float*)d_in[4];
    const float* W2   = (const float*)d_in[5];
    float* out        = (float*)d_out;

    // workspace layout; pre2b aliases pre1b (pre1b dead after spmm1)
    unsigned short* pre1b = (unsigned short*)d_ws;            // 6,400,000 ushort (12.8 MB)
    unsigned* hb          = (unsigned*)(pre1b + 6400000);     // 3,200,000 uint (12.8 MB)
    unsigned short* pre2b = pre1b;                            // alias
    unsigned long long* csr_ev = (unsigned long long*)(hb + 3200000);   // 800,000 u64 (6.4 MB)
    unsigned long long* tmp    = csr_ev + 800000;             // 196*6144 u64 (9.63 MB)
    int* row_ptr          = (int*)(tmp + (size_t)NBUCK * REG_STRIDE);   // 50,001 (pad 50,048)
    int* gcursor          = row_ptr + 50048;                  // 256
    unsigned short* W1t   = (unsigned short*)(gcursor + 256); // 65,536 ushort

    hipLaunchKernelGGL(w1conv_k,   dim3(256),  dim3(256), 0, stream, W1, W1t, gcursor);
    hipLaunchKernelGGL(bucket1_k,  dim3(391),  dim3(256), 0, stream, esrc, edst, ev, gcursor, tmp);
    hipLaunchKernelGGL(bucket2_k,  dim3(NBUCK),dim3(256), 0, stream, gcursor, tmp, csr_ev, row_ptr);

    hipLaunchKernelGGL(gemm1_mfma, dim3(782),  dim3(256), 0, stream, x, W1t, pre1b);
    hipLaunchKernelGGL(spmm1_k,    dim3(12500),dim3(256), 0, stream, row_ptr, csr_ev, (const unsigned*)pre1b, hb);
    hipLaunchKernelGGL(gemm2_k,    dim3(1563), dim3(256), 0, stream, hb, W2, pre2b);
    hipLaunchKernelGGL(spmm2_k,    dim3(12500),dim3(256), 0, stream, row_ptr, csr_ev, (const unsigned*)pre2b, out);
}